// Round 3
// baseline (2134.718 us; speedup 1.0000x reference)
//
#include <hip/hip_runtime.h>

#define NSLOTS 2048
#define DIM    512
#define BM     32

typedef __bf16 bf16x8 __attribute__((ext_vector_type(8)));
typedef float  f32x4  __attribute__((ext_vector_type(4)));
typedef unsigned short us4 __attribute__((ext_vector_type(4)));
typedef unsigned short us8 __attribute__((ext_vector_type(8)));

__device__ __forceinline__ unsigned short f2bf(float f) {
    unsigned u = __builtin_bit_cast(unsigned, f);
    u = (u + 0x7FFFu + ((u >> 16) & 1u)) >> 16;   // RNE
    return (unsigned short)u;
}
__device__ __forceinline__ float bf2f(unsigned short u) {
    unsigned v = ((unsigned)u) << 16;
    return __builtin_bit_cast(float, v);
}

// prep: 64 WGs x 512 thr; WG handles 32 slots.
// memN2 = L2-normalized memory in GEMM1 B-fragment order:
//   short idx = (((slot>>8)*16 + ((slot>>4)&15))*16 + (k>>5))*512
//               + ((k>>3)&3)*128 + (slot&15)*8 + (k&7)
// memT2 = raw memory in GEMM2 B-fragment order (d = dim, s = slot):
//   short idx = ((((d>>6)*8 + (s>>8))*8 + ((s>>5)&7))*4 + (d&3))*512
//               + ((s>>3)&3)*128 + ((d>>2)&15)*8 + (s&7)
// With these layouts every B-fragment load in the fused kernel is one
// contiguous 1KB wave transaction (16B/lane), not a 16-line gather.
__global__ __launch_bounds__(512) void prep_kernel(const float* __restrict__ mem,
                                                   unsigned short* __restrict__ memN2,
                                                   unsigned short* __restrict__ memT2) {
    __shared__ unsigned short T[32][516];
    const int tid = threadIdx.x;
    const int sl  = tid >> 4;        // local slot 0..31
    const int c16 = tid & 15;        // covers k in [c16*32, c16*32+32)
    const int n   = blockIdx.x * 32 + sl;
    const f32x4* row = (const f32x4*)(mem + (size_t)n * DIM);
    f32x4 v[8];
    float s = 0.f;
    #pragma unroll
    for (int j = 0; j < 8; ++j) {
        v[j] = row[c16*8 + j];
        s += v[j][0]*v[j][0] + v[j][1]*v[j][1] + v[j][2]*v[j][2] + v[j][3]*v[j][3];
    }
    #pragma unroll
    for (int off = 1; off < 16; off <<= 1) s += __shfl_xor(s, off);
    const float rn = 1.0f / fmaxf(sqrtf(s), 1e-12f);
    // stage raw bf16 for the dim-major shuffle
    #pragma unroll
    for (int j = 0; j < 8; ++j) {
        us4 q;
        #pragma unroll
        for (int e = 0; e < 4; ++e) q[e] = f2bf(v[j][e]);
        *(us4*)(&T[sl][c16*32 + j*4]) = q;
    }
    // memN2 fragments (normalized): 4 frags of 8 consecutive k
    {
        const size_t offbase = (((size_t)(n >> 8) * 16 + ((n >> 4) & 15)) * 16 + c16) * 512
                             + (size_t)(n & 15) * 8;
        #pragma unroll
        for (int f = 0; f < 4; ++f) {
            us8 p;
            #pragma unroll
            for (int e = 0; e < 4; ++e) {
                p[e]     = f2bf(v[f*2][e]   * rn);
                p[e + 4] = f2bf(v[f*2+1][e] * rn);
            }
            *(us8*)(memN2 + offbase + f*128) = p;
        }
    }
    __syncthreads();
    // memT2 fragments (raw): thread owns dim d = tid, slot-groups sg=0..3
    {
        const int d = tid;
        const int wid2 = d >> 6, l16c = (d >> 2) & 15, dt = d & 3;
        #pragma unroll
        for (int sg = 0; sg < 4; ++sg) {
            const int s0 = blockIdx.x * 32 + sg * 8;
            const int c = s0 >> 8, kk2 = (s0 >> 5) & 7, l4c = (s0 >> 3) & 3;
            us8 g;
            #pragma unroll
            for (int j = 0; j < 8; ++j) g[j] = T[sg*8 + j][d];
            const size_t off = ((((size_t)wid2*8 + c)*8 + kk2)*4 + dt)*512
                             + (size_t)(l4c*16 + l16c)*8;
            *(us8*)(memT2 + off) = g;
        }
    }
}

// One WG = 8 waves = 32 z-rows. Wave w owns slot-chunk [w*256, w*256+256).
__global__ __launch_bounds__(512) void fused_kernel(
    const float* __restrict__ z,
    const unsigned short* __restrict__ memN2,
    const unsigned short* __restrict__ memT2,
    float* __restrict__ zhat,
    float* __restrict__ attn)
{
    union ShU {
        unsigned short zn[BM][DIM];        // 32 KB, phase 0/1 (XOR-swizzled rows)
        unsigned short pbuf[2][BM][256];   // 2x16 KB, phase 2 (XOR-swizzled rows)
    };
    __shared__ ShU sh;
    __shared__ float wsums[8][BM];
    __shared__ float rsum[BM];

    const int tid  = threadIdx.x;
    const int wid  = tid >> 6;
    const int lane = tid & 63;
    const int l16  = lane & 15;
    const int l4   = lane >> 4;
    const size_t rowbase = (size_t)blockIdx.x * BM;

    // ---- phase 0: load z block (NT), L2-normalize rows, store bf16 to swizzled LDS ----
    {
        const int r   = tid >> 4;    // 0..31 (row)
        const int c16 = tid & 15;
        const f32x4* zr = (const f32x4*)(z + (rowbase + r) * DIM);
        f32x4 v[8];
        float s = 0.f;
        #pragma unroll
        for (int j = 0; j < 8; ++j) {
            v[j] = __builtin_nontemporal_load(zr + c16 + j*16);
            s += v[j][0]*v[j][0] + v[j][1]*v[j][1] + v[j][2]*v[j][2] + v[j][3]*v[j][3];
        }
        #pragma unroll
        for (int off = 1; off < 16; off <<= 1) s += __shfl_xor(s, off);
        const float rn = 1.0f / fmaxf(sqrtf(s), 1e-12f);
        char* znb = (char*)&sh.zn[r][0];
        #pragma unroll
        for (int j = 0; j < 8; ++j) {
            us4 p;
            #pragma unroll
            for (int e = 0; e < 4; ++e) p[e] = f2bf(v[j][e] * rn);
            const int byteoff = ((c16*4 + j*64) * 2) ^ ((r & 7) << 4);
            *(us4*)(znb + byteoff) = p;
        }
    }
    __syncthreads();

    // ---- phase 1: GEMM1  S[32][256] = zn @ memN^T (wave's chunk), K=512 ----
    const f32x4 zeroV = {0.f, 0.f, 0.f, 0.f};
    f32x4 acc[2][16];
    #pragma unroll
    for (int mt = 0; mt < 2; ++mt)
        #pragma unroll
        for (int nt = 0; nt < 16; ++nt) acc[mt][nt] = zeroV;
    {
        const unsigned short* bbase = memN2 + (size_t)wid * 131072 + (size_t)lane * 8;
        const char* znb = (const char*)&sh.zn[0][0];
        for (int kk = 0; kk < 16; ++kk) {
            bf16x8 a[2];
            #pragma unroll
            for (int mt = 0; mt < 2; ++mt) {
                const int r = mt*16 + l16;
                const int byteoff = r*1024 + ((kk*64 + l4*16) ^ ((r & 7) << 4));
                a[mt] = *(const bf16x8*)(znb + byteoff);
            }
            #pragma unroll
            for (int nt = 0; nt < 16; ++nt) {
                bf16x8 b = *(const bf16x8*)(bbase + ((nt*16 + kk) << 9));
                acc[0][nt] = __builtin_amdgcn_mfma_f32_16x16x32_bf16(a[0], b, acc[0][nt], 0, 0, 0);
                acc[1][nt] = __builtin_amdgcn_mfma_f32_16x16x32_bf16(a[1], b, acc[1][nt], 0, 0, 0);
            }
        }
    }

    // ---- exp (no max-sub needed: |logit| <= ~1) + row sums ----
    float psum[8];
    #pragma unroll
    for (int i = 0; i < 8; ++i) psum[i] = 0.f;
    #pragma unroll
    for (int mt = 0; mt < 2; ++mt)
        #pragma unroll
        for (int nt = 0; nt < 16; ++nt)
            #pragma unroll
            for (int r = 0; r < 4; ++r) {
                const float e = __expf(acc[mt][nt][r]);
                acc[mt][nt][r] = e;
                psum[mt*4 + r] += e;
            }
    #pragma unroll
    for (int i = 0; i < 8; ++i)
        #pragma unroll
        for (int off = 1; off < 16; off <<= 1) psum[i] += __shfl_xor(psum[i], off);
    if (l16 == 0) {
        #pragma unroll
        for (int mt = 0; mt < 2; ++mt)
            #pragma unroll
            for (int r = 0; r < 4; ++r)
                wsums[wid][mt*16 + l4*4 + r] = psum[mt*4 + r];
    }
    __syncthreads();
    if (tid < BM) {
        float t = 0.f;
        #pragma unroll
        for (int w = 0; w < 8; ++w) t += wsums[w][tid];
        rsum[tid] = 1.0f / t;
    }
    __syncthreads();

    float rs[2][4];
    #pragma unroll
    for (int mt = 0; mt < 2; ++mt)
        #pragma unroll
        for (int r = 0; r < 4; ++r) rs[mt][r] = rsum[mt*16 + l4*4 + r];
    const float sc_attn = rsum[tid >> 4];   // scale for the attn-write row this thread owns

    // ---- phase 2: GEMM2 z_hat = P @ memory (K=2048 chunked) + coalesced attn writes ----
    f32x4 acc2[2][4];
    #pragma unroll
    for (int mt = 0; mt < 2; ++mt)
        #pragma unroll
        for (int dt = 0; dt < 4; ++dt) acc2[mt][dt] = zeroV;

    auto dump = [&](int buf) {   // owner wave dumps its exp(S) chunk -> swizzled LDS bf16
        char* pb = (char*)&sh.pbuf[buf][0][0];
        #pragma unroll
        for (int mt = 0; mt < 2; ++mt)
            #pragma unroll
            for (int r = 0; r < 4; ++r) {
                const int row = mt*16 + l4*4 + r;
                char* pr = pb + row*512;
                #pragma unroll
                for (int nt = 0; nt < 16; ++nt) {
                    const int byteoff = ((nt*16 + l16)*2) ^ ((row & 7) << 4);
                    *(unsigned short*)(pr + byteoff) = f2bf(acc[mt][nt][r]);
                }
            }
    };

    if (wid == 0) dump(0);
    __syncthreads();

    const unsigned short* b2base = memT2 + (size_t)wid * 131072 + (size_t)lane * 8;

    for (int c = 0; c < 8; ++c) {
        if (wid == c + 1) dump((c + 1) & 1);             // prefetch next chunk's P

        // ---- coalesced attn write for chunk c (all 512 threads) ----
        {
            const int r   = tid >> 4;
            const int c16 = tid & 15;
            const char* pb = (const char*)&sh.pbuf[c & 1][0][0];
            float* abase = attn + (rowbase + r) * (size_t)NSLOTS + c*256;
            #pragma unroll
            for (int q = 0; q < 4; ++q) {
                const int byteoff = r*512 + ((q*128 + c16*8) ^ ((r & 7) << 4));
                us4 pv = *(const us4*)(pb + byteoff);
                f32x4 o;
                #pragma unroll
                for (int e = 0; e < 4; ++e) o[e] = bf2f(pv[e]) * sc_attn;
                __builtin_nontemporal_store(o, (f32x4*)(abase + q*64 + c16*4));
            }
        }

        // ---- GEMM2 MFMA on chunk c ----
        {
            const char* pb = (const char*)&sh.pbuf[c & 1][0][0];
            for (int kk = 0; kk < 8; ++kk) {
                bf16x8 a[2];
                #pragma unroll
                for (int mt = 0; mt < 2; ++mt) {
                    const int row = mt*16 + l16;
                    const int byteoff = row*512 + ((kk*64 + l4*16) ^ ((row & 7) << 4));
                    a[mt] = *(const bf16x8*)(pb + byteoff);
                }
                #pragma unroll
                for (int dt = 0; dt < 4; ++dt) {
                    bf16x8 b = *(const bf16x8*)(b2base + (((c*8 + kk)*4 + dt) << 9));
                    acc2[0][dt] = __builtin_amdgcn_mfma_f32_16x16x32_bf16(a[0], b, acc2[0][dt], 0, 0, 0);
                    acc2[1][dt] = __builtin_amdgcn_mfma_f32_16x16x32_bf16(a[1], b, acc2[1][dt], 0, 0, 0);
                }
            }
        }
        __syncthreads();
    }

    // ---- epilogue: z_hat = acc2 * (1/sum), float4 contiguous (dims l16*4..l16*4+3) ----
    {
        float* zbase = zhat + rowbase * DIM + wid*64;
        #pragma unroll
        for (int mt = 0; mt < 2; ++mt)
            #pragma unroll
            for (int r = 0; r < 4; ++r) {
                const int row = mt*16 + l4*4 + r;
                f32x4 o;
                #pragma unroll
                for (int dt = 0; dt < 4; ++dt) o[dt] = acc2[mt][dt][r] * rs[mt][r];
                __builtin_nontemporal_store(o, (f32x4*)(zbase + (size_t)row * DIM + l16*4));
            }
    }
}

extern "C" void kernel_launch(void* const* d_in, const int* in_sizes, int n_in,
                              void* d_out, int out_size, void* d_ws, size_t ws_size,
                              hipStream_t stream) {
    const float* zin = (const float*)d_in[0];
    const float* mem = (const float*)d_in[1];
    const int B = in_sizes[0] / DIM;                     // 65536
    unsigned short* memN2 = (unsigned short*)d_ws;       // 2 MB
    unsigned short* memT2 = memN2 + (size_t)NSLOTS * DIM; // 2 MB
    float* zhat = (float*)d_out;
    float* attn = zhat + (size_t)B * DIM;
    prep_kernel<<<NSLOTS / 32, 512, 0, stream>>>(mem, memN2, memT2);
    fused_kernel<<<B / BM, 512, 0, stream>>>(zin, memN2, memT2, zhat, attn);
}

// Round 4
// 1913.915 us; speedup vs baseline: 1.1154x; 1.1154x over previous
//
#include <hip/hip_runtime.h>

#define NSLOTS 2048
#define DIM    512

typedef __bf16 bf16x8 __attribute__((ext_vector_type(8)));
typedef float  f32x4  __attribute__((ext_vector_type(4)));
typedef unsigned short us4 __attribute__((ext_vector_type(4)));
typedef unsigned short us8 __attribute__((ext_vector_type(8)));

__device__ __forceinline__ unsigned short f2bf(float f) {
    unsigned u = __builtin_bit_cast(unsigned, f);
    u = (u + 0x7FFFu + ((u >> 16) & 1u)) >> 16;   // RNE
    return (unsigned short)u;
}
__device__ __forceinline__ float bf2f(unsigned short u) {
    unsigned v = ((unsigned)u) << 16;
    return __builtin_bit_cast(float, v);
}

// Frag-space LDS address with XOR swizzle: frag-stride 1024B, q = (s>>3)&3 quarter,
// r15 = row&15 slot, b = byte within 16B. Swizzle kills the frag/q-uniform bank aliasing.
__device__ __forceinline__ int LB(int frag, int q, int r15, int b) {
    return (frag << 10) + (q << 8) + (((r15 ^ (frag & 7) ^ q) & 15) << 4) + b;
}

// prep: memN2 = normalized memory, frag-linear for GEMM1 B:
//   idx = ((s>>4)*16 + (k>>5))*512 + ((k>>3)&3)*128 + (s&15)*8 + (k&7)
// memT2 = raw memory transposed, frag-linear for GEMM2 B:
//   idx = ((d>>4)*64 + (s>>5))*512 + ((s>>3)&3)*128 + (d&15)*8 + (s&7)
__global__ __launch_bounds__(512) void prep_kernel(const float* __restrict__ mem,
                                                   unsigned short* __restrict__ memN2,
                                                   unsigned short* __restrict__ memT2) {
    __shared__ unsigned short T[32][516];
    const int tid = threadIdx.x;
    const int sl  = tid >> 4;
    const int c16 = tid & 15;
    const int n   = blockIdx.x * 32 + sl;
    const f32x4* row = (const f32x4*)(mem + (size_t)n * DIM);
    f32x4 v[8];
    float s = 0.f;
    #pragma unroll
    for (int j = 0; j < 8; ++j) {
        v[j] = row[c16*8 + j];
        s += v[j][0]*v[j][0] + v[j][1]*v[j][1] + v[j][2]*v[j][2] + v[j][3]*v[j][3];
    }
    #pragma unroll
    for (int off = 1; off < 16; off <<= 1) s += __shfl_xor(s, off);
    const float rn = 1.0f / fmaxf(sqrtf(s), 1e-12f);
    #pragma unroll
    for (int j = 0; j < 8; ++j) {
        us4 q;
        #pragma unroll
        for (int e = 0; e < 4; ++e) q[e] = f2bf(v[j][e]);
        *(us4*)(&T[sl][c16*32 + j*4]) = q;
    }
    // memN2: thread covers k in [c16*32, +32) for slot n
    {
        const size_t offbase = (((size_t)(n >> 4)) * 16 + c16) * 512 + (size_t)(n & 15) * 8;
        #pragma unroll
        for (int f = 0; f < 4; ++f) {   // f = (k>>3)&3
            us8 p;
            #pragma unroll
            for (int e = 0; e < 4; ++e) {
                p[e]     = f2bf(v[f*2][e]   * rn);
                p[e + 4] = f2bf(v[f*2+1][e] * rn);
            }
            *(us8*)(memN2 + offbase + f*128) = p;
        }
    }
    __syncthreads();
    // memT2: thread owns dim d = tid, 4 slot-octs
    {
        const int d = tid;
        #pragma unroll
        for (int sg = 0; sg < 4; ++sg) {
            const int s0 = blockIdx.x * 32 + sg * 8;
            us8 g;
            #pragma unroll
            for (int j = 0; j < 8; ++j) g[j] = T[sg*8 + j][d];
            const size_t off = ((size_t)(d >> 4) * 64 + (s0 >> 5)) * 512
                             + (size_t)((s0 >> 3) & 3) * 128 + (size_t)(d & 15) * 8;
            *(us8*)(memT2 + off) = g;
        }
    }
}

// K1: 1024 WGs x 256 thr (4 waves, 2M x 2N). 64 rows/WG.
// Streams memN2 (2MB, L2-resident), writes unnormalized bf16 P into attn-region
// upper-half of each row slot ([row*8192 + 4096, +4096) bytes) + row sums.
__global__ __launch_bounds__(256) void k1_kernel(const float* __restrict__ z,
                                                 const unsigned short* __restrict__ memN2,
                                                 float* attnbase,
                                                 float* __restrict__ sums) {
    __shared__ char Pb[32768];
    __shared__ float wsums[2][64];
    const int tid  = threadIdx.x;
    const int wid  = tid >> 6;
    const int lane = tid & 63;
    const int l16  = lane & 15;
    const int l4   = lane >> 4;
    const int m    = wid >> 1, n = wid & 1;
    const size_t rowbase = (size_t)blockIdx.x * 64;

    // ---- load z rows -> f32 regs, row norms, pack bf16 A-fragments ----
    f32x4 v[2][16][2];
    float ps[2] = {0.f, 0.f};
    #pragma unroll
    for (int mt = 0; mt < 2; ++mt) {
        const int row = (int)rowbase + m*32 + mt*16 + l16;
        const f32x4* zr = (const f32x4*)(z + (size_t)row * DIM);
        #pragma unroll
        for (int kk = 0; kk < 16; ++kk) {
            v[mt][kk][0] = __builtin_nontemporal_load(zr + kk*8 + l4*2);
            v[mt][kk][1] = __builtin_nontemporal_load(zr + kk*8 + l4*2 + 1);
            #pragma unroll
            for (int h = 0; h < 2; ++h)
                ps[mt] += v[mt][kk][h][0]*v[mt][kk][h][0] + v[mt][kk][h][1]*v[mt][kk][h][1]
                        + v[mt][kk][h][2]*v[mt][kk][h][2] + v[mt][kk][h][3]*v[mt][kk][h][3];
        }
    }
    #pragma unroll
    for (int mt = 0; mt < 2; ++mt) {
        ps[mt] += __shfl_xor(ps[mt], 16);
        ps[mt] += __shfl_xor(ps[mt], 32);
    }
    bf16x8 a[2][16];
    #pragma unroll
    for (int mt = 0; mt < 2; ++mt) {
        const float rn = 1.0f / fmaxf(sqrtf(ps[mt]), 1e-12f);
        #pragma unroll
        for (int kk = 0; kk < 16; ++kk) {
            us8 p;
            #pragma unroll
            for (int e = 0; e < 8; ++e) p[e] = f2bf(v[mt][kk][e >> 2][e & 3] * rn);
            a[mt][kk] = __builtin_bit_cast(bf16x8, p);
        }
    }

    // ---- chunk loop over slots ----
    const f32x4 zeroV = {0.f, 0.f, 0.f, 0.f};
    float psum[2][4];
    #pragma unroll
    for (int mt = 0; mt < 2; ++mt)
        #pragma unroll
        for (int r = 0; r < 4; ++r) psum[mt][r] = 0.f;

    for (int c = 0; c < 8; ++c) {
        f32x4 acc[2][8];
        #pragma unroll
        for (int mt = 0; mt < 2; ++mt)
            #pragma unroll
            for (int nt = 0; nt < 8; ++nt) acc[mt][nt] = zeroV;
        const unsigned short* bb = memN2 + ((size_t)(c*16 + n*8) * 16) * 512 + (size_t)lane * 8;
        for (int kk = 0; kk < 16; ++kk) {
            #pragma unroll
            for (int nt = 0; nt < 8; ++nt) {
                bf16x8 b = *(const bf16x8*)(bb + (size_t)(nt*16 + kk) * 512);
                acc[0][nt] = __builtin_amdgcn_mfma_f32_16x16x32_bf16(a[0][kk], b, acc[0][nt], 0, 0, 0);
                acc[1][nt] = __builtin_amdgcn_mfma_f32_16x16x32_bf16(a[1][kk], b, acc[1][nt], 0, 0, 0);
            }
        }
        __syncthreads();   // protect Pb readers of previous chunk
        #pragma unroll
        for (int mt = 0; mt < 2; ++mt)
            #pragma unroll
            for (int nt = 0; nt < 8; ++nt)
                #pragma unroll
                for (int r = 0; r < 4; ++r) {
                    const float e = __expf(acc[mt][nt][r]);
                    psum[mt][r] += e;
                    const int rl = m*32 + mt*16 + l4*4 + r;
                    const int sl = n*128 + nt*16 + l16;
                    const int frag = ((rl >> 4) << 3) + (sl >> 5);
                    *(unsigned short*)(Pb + LB(frag, (sl >> 3) & 3, rl & 15, (sl & 7) * 2)) = f2bf(e);
                }
        __syncthreads();
        // bounce-out: linear-ish coalesced NT stores of the 32KB chunk
        {
            const int r = tid >> 2, q = tid & 3;
            char* gdst = (char*)attnbase + (rowbase + r) * 8192 + 4096 + c*512 + q*16;
            #pragma unroll
            for (int j = 0; j < 8; ++j) {
                us8 pv = *(const us8*)(Pb + LB(((r >> 4) << 3) + j, q, r & 15, 0));
                __builtin_nontemporal_store(pv, (us8*)(gdst + j*64));
            }
        }
    }

    // ---- row sums ----
    #pragma unroll
    for (int mt = 0; mt < 2; ++mt)
        #pragma unroll
        for (int r = 0; r < 4; ++r) {
            #pragma unroll
            for (int off = 1; off < 16; off <<= 1) psum[mt][r] += __shfl_xor(psum[mt][r], off);
        }
    if (l16 == 0) {
        #pragma unroll
        for (int mt = 0; mt < 2; ++mt)
            #pragma unroll
            for (int r = 0; r < 4; ++r)
                wsums[n][m*32 + mt*16 + l4*4 + r] = psum[mt][r];
    }
    __syncthreads();
    if (tid < 64) sums[rowbase + tid] = wsums[0][tid] + wsums[1][tid];
}

// K2: 1024 WGs x 512 thr (8 waves, 2M x 4N). 64 rows/WG, all 512 dims.
// Reads bf16 P chunks (written by K1) + memT2 (2MB, L2-resident);
// writes normalized fp32 attn + zhat.
__global__ __launch_bounds__(512, 4) void k2_kernel(const unsigned short* __restrict__ memT2,
                                                    const float* __restrict__ sums,
                                                    float* __restrict__ zhat,
                                                    float* attnbase) {
    __shared__ char Ab[32768];
    __shared__ float rsums[64];
    const int tid  = threadIdx.x;
    const int wid  = tid >> 6;
    const int lane = tid & 63;
    const int l16  = lane & 15;
    const int l4   = lane >> 4;
    const int m    = wid >> 2, n = wid & 3;
    const size_t rowbase = (size_t)blockIdx.x * 64;

    if (tid < 64) rsums[tid] = 1.0f / sums[rowbase + tid];

    const f32x4 zeroV = {0.f, 0.f, 0.f, 0.f};
    f32x4 acc[2][8];
    #pragma unroll
    for (int mt = 0; mt < 2; ++mt)
        #pragma unroll
        for (int dt = 0; dt < 8; ++dt) acc[mt][dt] = zeroV;

    // per-lane B base: d = n*128 + l16*8 + dt, frag_d = n*8 + (l16>>1), d&15 = (l16&1)*8 + dt
    const unsigned short* bbase = memT2 + ((size_t)(n*8 + (l16 >> 1)) * 64) * 512
                                + (size_t)l4 * 128 + (size_t)(l16 & 1) * 64;
    const int r8 = tid >> 3;       // 0..63 (row for stage/attn-write phases)

    for (int c = 0; c < 8; ++c) {
        // load this chunk's bf16 P (64 rows x 256 slots) from attn-region upper halves
        us8 av[4];
        {
            const char* gsrc = (const char*)attnbase + (rowbase + r8) * 8192 + 4096 + c*512;
            #pragma unroll
            for (int k = 0; k < 4; ++k) {
                const int soct = (tid & 7) + k*8;
                av[k] = __builtin_nontemporal_load((const us8*)(gsrc + soct*16));
            }
        }
        __syncthreads();   // protect previous chunk's readers
        #pragma unroll
        for (int k = 0; k < 4; ++k) {
            const int soct = (tid & 7) + k*8;
            *(us8*)(Ab + LB(((r8 >> 4) << 3) + (soct >> 2), soct & 3, r8 & 15, 0)) = av[k];
        }
        __syncthreads();

        // normalized fp32 attn writes for this chunk (stores fly during MFMA)
        {
            const float sc = rsums[r8];
            char* gdst = (char*)attnbase + (rowbase + r8) * 8192 + (size_t)c * 1024 + (tid & 7) * 16;
            #pragma unroll
            for (int j = 0; j < 8; ++j) {
                us4 pv = *(const us4*)(Ab + LB(((r8 >> 4) << 3) + j, (tid >> 1) & 3, r8 & 15, (tid & 1) * 8));
                f32x4 o;
                #pragma unroll
                for (int e = 0; e < 4; ++e) o[e] = bf2f(pv[e]) * sc;
                __builtin_nontemporal_store(o, (f32x4*)(gdst + j*128));
            }
        }

        // GEMM2 MFMA on this chunk
        for (int kk = 0; kk < 8; ++kk) {
            bf16x8 a[2];
            #pragma unroll
            for (int mt = 0; mt < 2; ++mt)
                a[mt] = *(const bf16x8*)(Ab + LB(((m*2 + mt) << 3) + kk, l4, l16, 0));
            #pragma unroll
            for (int dt = 0; dt < 8; ++dt) {
                bf16x8 b = *(const bf16x8*)(bbase + (size_t)(c*8 + kk) * 512 + dt*8);
                acc[0][dt] = __builtin_amdgcn_mfma_f32_16x16x32_bf16(a[0], b, acc[0][dt], 0, 0, 0);
                acc[1][dt] = __builtin_amdgcn_mfma_f32_16x16x32_bf16(a[1], b, acc[1][dt], 0, 0, 0);
            }
        }
    }

    // epilogue: zhat, 8 consecutive dims per lane (d = n*128 + l16*8 + dt)
    #pragma unroll
    for (int mt = 0; mt < 2; ++mt)
        #pragma unroll
        for (int r = 0; r < 4; ++r) {
            const int rl = m*32 + mt*16 + l4*4 + r;
            const float rs = rsums[rl];
            float* zr = zhat + (rowbase + rl) * DIM + n*128 + l16*8;
            f32x4 o0, o1;
            #pragma unroll
            for (int dt = 0; dt < 4; ++dt) { o0[dt] = acc[mt][dt][r] * rs; o1[dt] = acc[mt][dt+4][r] * rs; }
            __builtin_nontemporal_store(o0, (f32x4*)zr);
            __builtin_nontemporal_store(o1, (f32x4*)(zr + 4));
        }
}

extern "C" void kernel_launch(void* const* d_in, const int* in_sizes, int n_in,
                              void* d_out, int out_size, void* d_ws, size_t ws_size,
                              hipStream_t stream) {
    const float* zin = (const float*)d_in[0];
    const float* mem = (const float*)d_in[1];
    const int B = in_sizes[0] / DIM;                       // 65536
    unsigned short* memN2 = (unsigned short*)d_ws;         // 2 MB
    unsigned short* memT2 = memN2 + (size_t)NSLOTS * DIM;  // 2 MB
    float* sums = (float*)(memT2 + (size_t)NSLOTS * DIM);  // 256 KB
    float* zhat = (float*)d_out;
    float* attn = zhat + (size_t)B * DIM;
    prep_kernel<<<NSLOTS / 32, 512, 0, stream>>>(mem, memN2, memT2);
    k1_kernel<<<B / 64, 256, 0, stream>>>(zin, memN2, attn, sums);
    k2_kernel<<<B / 64, 512, 0, stream>>>(memT2, sums, zhat, attn);
}

// Round 5
// 554.084 us; speedup vs baseline: 3.8527x; 3.4542x over previous
//
#include <hip/hip_runtime.h>

#define NSLOTS 2048
#define DIM    512

typedef __bf16 bf16x8 __attribute__((ext_vector_type(8)));
typedef float  f32x4  __attribute__((ext_vector_type(4)));
typedef unsigned short us4 __attribute__((ext_vector_type(4)));
typedef unsigned short us8 __attribute__((ext_vector_type(8)));

typedef const __attribute__((address_space(1))) unsigned* gp_t;
typedef __attribute__((address_space(3))) unsigned* sp_t;

__device__ __forceinline__ void gl16(const void* g, void* l) {
    __builtin_amdgcn_global_load_lds((gp_t)g, (sp_t)l, 16, 0, 0);
}

__device__ __forceinline__ unsigned short f2bf(float f) {
    unsigned u = __builtin_bit_cast(unsigned, f);
    u = (u + 0x7FFFu + ((u >> 16) & 1u)) >> 16;   // RNE
    return (unsigned short)u;
}
__device__ __forceinline__ float bf2f(unsigned short u) {
    unsigned v = ((unsigned)u) << 16;
    return __builtin_bit_cast(float, v);
}

// prep: memN = L2-normalized memory [2048][512] bf16 (row-major);
//       memT = raw memory transposed [512][2048] bf16 (row-major).
__global__ __launch_bounds__(512) void prep_kernel(const float* __restrict__ mem,
                                                   unsigned short* __restrict__ memN,
                                                   unsigned short* __restrict__ memT) {
    __shared__ unsigned short T[32][516];
    const int tid = threadIdx.x;
    const int sl  = tid >> 4;
    const int c16 = tid & 15;
    const int n   = blockIdx.x * 32 + sl;
    const f32x4* row = (const f32x4*)(mem + (size_t)n * DIM);
    f32x4 v[8];
    float s = 0.f;
    #pragma unroll
    for (int j = 0; j < 8; ++j) {
        v[j] = row[c16*8 + j];
        s += v[j][0]*v[j][0] + v[j][1]*v[j][1] + v[j][2]*v[j][2] + v[j][3]*v[j][3];
    }
    #pragma unroll
    for (int off = 1; off < 16; off <<= 1) s += __shfl_xor(s, off);
    const float rn = 1.0f / fmaxf(sqrtf(s), 1e-12f);
    #pragma unroll
    for (int j = 0; j < 8; ++j) {
        us4 p, q;
        #pragma unroll
        for (int e = 0; e < 4; ++e) { p[e] = f2bf(v[j][e] * rn); q[e] = f2bf(v[j][e]); }
        *(us4*)(memN + (size_t)n * DIM + c16*32 + j*4) = p;
        *(us4*)(&T[sl][c16*32 + j*4]) = q;
    }
    __syncthreads();
    {
        const int d = tid;
        const int c4 = tid & 3;
        #pragma unroll
        for (int i = 0; i < 4; ++i) {
            const int dd = i*128 + (tid >> 2);
            us8 g;
            #pragma unroll
            for (int j = 0; j < 8; ++j) g[j] = T[c4*8 + j][dd];
            *(us8*)(memT + (size_t)dd * NSLOTS + blockIdx.x*32 + c4*8) = g;
        }
        (void)d;
    }
}

// zprep: normalize z rows once -> bf16, stored in attn rows at byte offset 3072.
// 1024 WGs x 512 thr; 64 rows/WG, 8 threads/row.
__global__ __launch_bounds__(512) void zprep_kernel(const float* __restrict__ z,
                                                    float* attnB) {
    const int tid = threadIdx.x;
    const size_t row = (size_t)blockIdx.x * 64 + (tid >> 3);
    const int c8 = tid & 7;
    const f32x4* zr = (const f32x4*)(z + row * DIM);
    f32x4 v[16];
    float s = 0.f;
    #pragma unroll
    for (int j = 0; j < 16; ++j) {
        v[j] = __builtin_nontemporal_load(zr + c8 + j*8);
        s += v[j][0]*v[j][0] + v[j][1]*v[j][1] + v[j][2]*v[j][2] + v[j][3]*v[j][3];
    }
    s += __shfl_xor(s, 1); s += __shfl_xor(s, 2); s += __shfl_xor(s, 4);
    const float rn = 1.0f / fmaxf(sqrtf(s), 1e-12f);
    char* dst = (char*)attnB + row * 8192 + 3072;
    #pragma unroll
    for (int j = 0; j < 16; ++j) {
        us4 p;
        #pragma unroll
        for (int e = 0; e < 4; ++e) p[e] = f2bf(v[j][e] * rn);
        *(us4*)(dst + c8*8 + j*64) = p;
    }
}

// K1: GEMM1 + exp + row sums. 1024 WGs x 512 thr (8 waves = 2M x 4N).
// Tile: 64 rows x 128 slots, BK=64, 16 slot-chunks. LDS dbuf staging via global_load_lds.
// Writes bf16 P=exp(S) to attn-row upper halves (+4096), row sums to ws.
__global__ __launch_bounds__(512, 4) void k1_kernel(const unsigned short* __restrict__ memN,
                                                    float* attnB,
                                                    float* __restrict__ sums) {
    __shared__ char sb[2][24576];     // A 8KB + B 16KB per buffer
    __shared__ float wsums[4][64];
    const int tid  = threadIdx.x;
    const int wid  = tid >> 6;
    const int lane = tid & 63;
    const int l16  = lane & 15;
    const int l4   = lane >> 4;
    const int m    = wid >> 2, n = wid & 3;
    const size_t rowbase = (size_t)blockIdx.x * 64;
    const char* attnRd = (const char*)attnB;

    auto stage = [&](int buf, int t) {
        const int c = t >> 3, ks = t & 7;
        {   // A-tile [64 r][64 k]: 512 x 16B, one issue per wave
            const int f = wid*64 + lane, ar = f >> 3, g = f & 7;
            const char* src = attnRd + (rowbase + ar) * 8192 + 3072 + ks*128
                            + ((g*16) ^ ((ar & 7) << 4));
            gl16(src, &sb[buf][0] + wid*1024);
        }
        #pragma unroll
        for (int i = 0; i < 2; ++i) {   // B-tile [128 s][64 k]: 1024 x 16B
            const int f = (i*8 + wid)*64 + lane, br = f >> 3, g = f & 7;
            const char* src = (const char*)memN + (size_t)(c*128 + br) * 1024 + ks*128
                            + ((g*16) ^ ((br & 7) << 4));
            gl16(src, &sb[buf][8192] + (i*8 + wid)*1024);
        }
    };

    const f32x4 zeroV = {0.f, 0.f, 0.f, 0.f};
    f32x4 acc[2][2];
    #pragma unroll
    for (int mt = 0; mt < 2; ++mt)
        #pragma unroll
        for (int nt = 0; nt < 2; ++nt) acc[mt][nt] = zeroV;
    float psum[2][4];
    #pragma unroll
    for (int mt = 0; mt < 2; ++mt)
        #pragma unroll
        for (int r = 0; r < 4; ++r) psum[mt][r] = 0.f;

    stage(0, 0);
    __syncthreads();

    for (int t = 0; t < 128; ++t) {
        const int c = t >> 3, ks = t & 7;
        if (t < 127) stage((t + 1) & 1, t + 1);
        const char* Ab = (const char*)&sb[t & 1][0];
        const char* Bb = (const char*)&sb[t & 1][8192];
        #pragma unroll
        for (int kk = 0; kk < 2; ++kk) {
            bf16x8 af[2];
            #pragma unroll
            for (int mt = 0; mt < 2; ++mt) {
                const int ar = m*32 + mt*16 + l16;
                af[mt] = *(const bf16x8*)(Ab + ar*128 + ((kk*64 + l4*16) ^ ((ar & 7) << 4)));
            }
            #pragma unroll
            for (int nt = 0; nt < 2; ++nt) {
                const int br = n*32 + nt*16 + l16;
                bf16x8 b = *(const bf16x8*)(Bb + br*128 + ((kk*64 + l4*16) ^ ((br & 7) << 4)));
                acc[0][nt] = __builtin_amdgcn_mfma_f32_16x16x32_bf16(af[0], b, acc[0][nt], 0, 0, 0);
                acc[1][nt] = __builtin_amdgcn_mfma_f32_16x16x32_bf16(af[1], b, acc[1][nt], 0, 0, 0);
            }
        }
        __syncthreads();
        if (ks == 7) {
            // exp + psum + pack P chunk [64 r][128 s] bf16 into stale buffer
            char* Pl = (char*)&sb[t & 1][0];
            #pragma unroll
            for (int mt = 0; mt < 2; ++mt)
                #pragma unroll
                for (int nt = 0; nt < 2; ++nt)
                    #pragma unroll
                    for (int r = 0; r < 4; ++r) {
                        const float e = __expf(acc[mt][nt][r]);
                        psum[mt][r] += e;
                        const int row = m*32 + mt*16 + l4*4 + r;
                        const int sl  = n*32 + nt*16 + l16;
                        *(unsigned short*)(Pl + row*256 + (((sl >> 3) * 16) ^ ((row & 7) << 4)) + (sl & 7)*2) = f2bf(e);
                        acc[mt][nt][r] = 0.f;
                    }
            __syncthreads();
            {   // bounce out: coalesced NT stores to attn upper halves
                const int prow = tid >> 3;
                #pragma unroll
                for (int h = 0; h < 2; ++h) {
                    const int g = (tid & 7) + h*8;
                    us8 pv = *(const us8*)(Pl + prow*256 + ((g*16) ^ ((prow & 7) << 4)));
                    __builtin_nontemporal_store(pv,
                        (us8*)((char*)attnB + (rowbase + prow) * 8192 + 4096 + c*256 + g*16));
                }
            }
            __syncthreads();
        }
    }

    // row sums
    #pragma unroll
    for (int mt = 0; mt < 2; ++mt)
        #pragma unroll
        for (int r = 0; r < 4; ++r) {
            #pragma unroll
            for (int off = 1; off < 16; off <<= 1) psum[mt][r] += __shfl_xor(psum[mt][r], off);
        }
    if (l16 == 0) {
        #pragma unroll
        for (int mt = 0; mt < 2; ++mt)
            #pragma unroll
            for (int r = 0; r < 4; ++r)
                wsums[n][m*32 + mt*16 + l4*4 + r] = psum[mt][r];
    }
    __syncthreads();
    if (tid < 64) sums[rowbase + tid] = wsums[0][tid] + wsums[1][tid] + wsums[2][tid] + wsums[3][tid];
}

// K2: GEMM2 + normalized attn writes. 1024 WGs x 512 thr (8 waves = 2M x 4N).
// ks outer (32 slot-chunks of 64), nb inner (4 dim-blocks of 128). A=P staged once per ks.
__global__ __launch_bounds__(512, 4) void k2_kernel(const unsigned short* __restrict__ memT,
                                                    const float* __restrict__ sums,
                                                    float* __restrict__ zhat,
                                                    float* attnB) {
    __shared__ char ab[2][8192];      // A-tile [64 r][64 s]
    __shared__ char bb[2][16384];     // B-tile [128 d][64 s]
    __shared__ float rsums[64];
    const int tid  = threadIdx.x;
    const int wid  = tid >> 6;
    const int lane = tid & 63;
    const int l16  = lane & 15;
    const int l4   = lane >> 4;
    const int m    = wid >> 2, n = wid & 3;
    const size_t rowbase = (size_t)blockIdx.x * 64;
    const char* attnRd = (const char*)attnB;

    auto stageA = [&](int buf, int ks) {
        const int f = wid*64 + lane, ar = f >> 3, g = f & 7;
        const char* src = attnRd + (rowbase + ar) * 8192 + 4096 + ks*128
                        + ((g*16) ^ ((ar & 7) << 4));
        gl16(src, &ab[buf][0] + wid*1024);
    };
    auto stageB = [&](int buf, int ks, int nb) {
        #pragma unroll
        for (int i = 0; i < 2; ++i) {
            const int f = (i*8 + wid)*64 + lane, dr = f >> 3, g = f & 7;
            const char* src = (const char*)memT + (size_t)(nb*128 + dr) * 4096 + ks*128
                            + ((g*16) ^ ((dr & 7) << 4));
            gl16(src, &bb[buf][0] + (i*8 + wid)*1024);
        }
    };

    if (tid < 64) rsums[tid] = 1.0f / sums[rowbase + tid];

    const f32x4 zeroV = {0.f, 0.f, 0.f, 0.f};
    f32x4 acc[4][2][2];
    #pragma unroll
    for (int nb = 0; nb < 4; ++nb)
        #pragma unroll
        for (int mt = 0; mt < 2; ++mt)
            #pragma unroll
            for (int nt = 0; nt < 2; ++nt) acc[nb][mt][nt] = zeroV;

    stageA(0, 0);
    stageB(0, 0, 0);
    __syncthreads();

    for (int ks = 0; ks < 32; ++ks) {
        #pragma unroll
        for (int nb = 0; nb < 4; ++nb) {
            const int u = ks*4 + nb;
            if (nb < 3) stageB((u + 1) & 1, ks, nb + 1);
            else if (ks < 31) { stageA((ks + 1) & 1, ks + 1); stageB((u + 1) & 1, ks + 1, 0); }
            const char* Ab = (const char*)&ab[ks & 1][0];
            const char* Bb = (const char*)&bb[u & 1][0];
            if (nb == 0) {   // normalized fp32 attn write for chunk ks from staged P
                const int prow = tid >> 3;
                const int g = tid & 7;
                const float sc = rsums[prow];
                us8 pv = *(const us8*)(Ab + prow*128 + ((g*16) ^ ((prow & 7) << 4)));
                f32x4 o0, o1;
                #pragma unroll
                for (int e = 0; e < 4; ++e) { o0[e] = bf2f(pv[e]) * sc; o1[e] = bf2f(pv[e + 4]) * sc; }
                float* dst = attnB + (rowbase + prow) * NSLOTS + ks*64 + g*8;
                __builtin_nontemporal_store(o0, (f32x4*)dst);
                __builtin_nontemporal_store(o1, (f32x4*)(dst + 4));
            }
            #pragma unroll
            for (int kk = 0; kk < 2; ++kk) {
                bf16x8 af[2];
                #pragma unroll
                for (int mt = 0; mt < 2; ++mt) {
                    const int ar = m*32 + mt*16 + l16;
                    af[mt] = *(const bf16x8*)(Ab + ar*128 + ((kk*64 + l4*16) ^ ((ar & 7) << 4)));
                }
                #pragma unroll
                for (int nt = 0; nt < 2; ++nt) {
                    const int dr = n*32 + nt*16 + l16;
                    bf16x8 b = *(const bf16x8*)(Bb + dr*128 + ((kk*64 + l4*16) ^ ((dr & 7) << 4)));
                    acc[nb][0][nt] = __builtin_amdgcn_mfma_f32_16x16x32_bf16(af[0], b, acc[nb][0][nt], 0, 0, 0);
                    acc[nb][1][nt] = __builtin_amdgcn_mfma_f32_16x16x32_bf16(af[1], b, acc[nb][1][nt], 0, 0, 0);
                }
            }
            __syncthreads();
        }
    }

    // epilogue: zhat
    #pragma unroll
    for (int nb = 0; nb < 4; ++nb)
        #pragma unroll
        for (int mt = 0; mt < 2; ++mt)
            #pragma unroll
            for (int r = 0; r < 4; ++r) {
                const int row = m*32 + mt*16 + l4*4 + r;
                const float rs = rsums[row];
                float* zr = zhat + (rowbase + row) * DIM + nb*128 + n*32 + l16;
                __builtin_nontemporal_store(acc[nb][mt][0][r] * rs, zr);
                __builtin_nontemporal_store(acc[nb][mt][1][r] * rs, zr + 16);
            }
}

extern "C" void kernel_launch(void* const* d_in, const int* in_sizes, int n_in,
                              void* d_out, int out_size, void* d_ws, size_t ws_size,
                              hipStream_t stream) {
    const float* zin = (const float*)d_in[0];
    const float* mem = (const float*)d_in[1];
    const int B = in_sizes[0] / DIM;                       // 65536
    unsigned short* memN = (unsigned short*)d_ws;          // 2 MB
    unsigned short* memT = memN + (size_t)NSLOTS * DIM;    // 2 MB
    float* sums = (float*)(memT + (size_t)NSLOTS * DIM);   // 256 KB
    float* zhat = (float*)d_out;
    float* attn = zhat + (size_t)B * DIM;
    prep_kernel<<<NSLOTS / 32, 512, 0, stream>>>(mem, memN, memT);
    zprep_kernel<<<B / 64, 512, 0, stream>>>(zin, attn);
    k1_kernel<<<B / 64, 512, 0, stream>>>(memN, attn, sums);
    k2_kernel<<<B / 64, 512, 0, stream>>>(memT, sums, zhat, attn);
}